// Round 1
// baseline (309.834 us; speedup 1.0000x reference)
//
#include <hip/hip_runtime.h>

#define Bn 8
#define Nn 4096
#define Pn 4096
#define Kn 32
#define Cn 128
#define Wn 16
#define TP 16

using float4v = __attribute__((ext_vector_type(4))) float;
using short8  = __attribute__((ext_vector_type(8))) short;

__device__ __forceinline__ unsigned short bf16b(float f) {
  union { float f; unsigned u; } v; v.f = f;
  unsigned r = v.u + 0x7FFFu + ((v.u >> 16) & 1u);   // round-nearest-even
  return (unsigned short)(r >> 16);
}

// ---------------------------------------------------------------------------
// prep: WlT[n][k] = bf16(Wl[k][n])   (2048x128 -> 128x2048), 16 blocks
// ---------------------------------------------------------------------------
__global__ __launch_bounds__(256) void prep_wl(const float* __restrict__ Wl,
                                               unsigned short* __restrict__ WlT) {
  __shared__ unsigned short tile[128 * 130];
  const int t = threadIdx.x, blk = blockIdx.x;
#pragma unroll
  for (int i = 0; i < 64; ++i) {
    int idx = i * 256 + t;
    int kl = idx >> 7, n = idx & 127;
    tile[n * 130 + kl] = bf16b(Wl[(size_t)(blk * 128 + kl) * 128 + n]);
  }
  __syncthreads();
#pragma unroll
  for (int i = 0; i < 64; ++i) {
    int idx = i * 256 + t;
    int n = idx >> 7, kl = idx & 127;
    WlT[(size_t)n * 2048 + blk * 128 + kl] = tile[n * 130 + kl];
  }
}

// ---------------------------------------------------------------------------
// fused conv: weights -> gather -> stage1 MFMA (M=dataT^T@wts) -> stage2 MFMA
// (Y = Mflat @ Wl) -> bias -> transposed store + channel sum/sumsq atomics
// ---------------------------------------------------------------------------
__global__ __launch_bounds__(256, 2) void fused_conv(
    const float* __restrict__ points, const float* __restrict__ lc,
    const int* __restrict__ nl, const int* __restrict__ didx,
    const float* __restrict__ Ww, const float* __restrict__ bwv,
    const unsigned short* __restrict__ WlT, const float* __restrict__ blv,
    float* __restrict__ xout, float* __restrict__ gacc) {
  // LDS: 64 KB + 10 KB + 1.25 KB = 77 KB -> 2 blocks/CU
  __shared__ unsigned short Mflat[TP * 2048];   // swizzled: 16B block bI stored at bI^pi
  __shared__ unsigned short dataT[128 * 40];    // [c][k], pad 40 (16B-aligned rows)
  __shared__ unsigned short wtsT[16 * 40];      // [w][k], pad 40

  const int t = threadIdx.x;
  const int lane = t & 63;
  const int wave = t >> 6;
  const int b = blockIdx.x >> 8;
  const int p0 = (blockIdx.x & 255) * TP;
  const int db = didx[b];
  const float* __restrict__ pbat = points + (size_t)db * (Nn * Cn);
  const int l15 = lane & 15;
  const int q = lane >> 4;

  for (int pi = 0; pi < TP; ++pi) {
    const int p = p0 + pi;
    {  // weights: 256 threads x 2 entries -> wtsT (A-operand layout)
      const int k = t >> 3, w2 = (t & 7) * 2;
      const float* lcp = lc + ((size_t)(db * Pn + p) * Kn + k) * 3;
      const float l0 = lcp[0], l1 = lcp[1], l2 = lcp[2];
      float w0 = bwv[w2]     + l0 * Ww[w2]     + l1 * Ww[16 + w2]     + l2 * Ww[32 + w2];
      float w1 = bwv[w2 + 1] + l0 * Ww[w2 + 1] + l1 * Ww[16 + w2 + 1] + l2 * Ww[32 + w2 + 1];
      wtsT[w2 * 40 + k]       = bf16b(w0);
      wtsT[(w2 + 1) * 40 + k] = bf16b(w1);
    }
    {  // gather: thread (c = t&127, kh = t>>7) loads 16 k-rows, writes c-major bf16
      const int c = t & 127, kh = t >> 7;
      const int* nlp = nl + (size_t)(db * Pn + p) * Kn + kh * 16;
      int nk[16];
#pragma unroll
      for (int kk = 0; kk < 16; ++kk) nk[kk] = nlp[kk];
      unsigned short tv[16];
#pragma unroll
      for (int kk = 0; kk < 16; ++kk) tv[kk] = bf16b(pbat[nk[kk] * Cn + c]);
#pragma unroll
      for (int i = 0; i < 4; ++i) {
        ushort4 u;
        u.x = tv[4 * i]; u.y = tv[4 * i + 1]; u.z = tv[4 * i + 2]; u.w = tv[4 * i + 3];
        *(ushort4*)&dataT[c * 40 + kh * 16 + 4 * i] = u;
      }
    }
    __syncthreads();
    {  // stage 1: D[w][c_tile] = wts^T @ data ; 2 c-tiles per wave
      short8 af = *(const short8*)&wtsT[l15 * 40 + q * 8];
#pragma unroll
      for (int ct = 0; ct < 2; ++ct) {
        const int c = (wave * 2 + ct) * 16 + l15;
        short8 bfv = *(const short8*)&dataT[c * 40 + q * 8];
        float4v d = {0.f, 0.f, 0.f, 0.f};
        d = __builtin_amdgcn_mfma_f32_16x16x32_bf16(af, bfv, d, 0, 0, 0);
        // lane holds M[c][w = q*4 + r], r=0..3 -> 4 consecutive elems of Mflat row
        const int jidx = c * 16 + q * 4;
        const int bI = (jidx >> 3) ^ pi;
        ushort4 u;
        u.x = bf16b(d[0]); u.y = bf16b(d[1]); u.z = bf16b(d[2]); u.w = bf16b(d[3]);
        *(ushort4*)&Mflat[pi * 2048 + (bI << 3) + (jidx & 7)] = u;
      }
    }
    __syncthreads();
  }

  // stage 2: Y(16x128) = Mflat(16x2048) @ Wl(2048x128); wave owns cols [32w,32w+32)
  const int n0 = wave * 32;
  const unsigned short* w0p = WlT + (size_t)(n0 + l15) * 2048 + q * 8;
  const unsigned short* w1p = w0p + 16 * 2048;
  float4v acc0 = {0.f, 0.f, 0.f, 0.f}, acc1 = {0.f, 0.f, 0.f, 0.f};
#pragma unroll 4
  for (int kk = 0; kk < 64; ++kk) {
    short8 a  = *(const short8*)&Mflat[l15 * 2048 + (((kk * 4 + q) ^ l15) << 3)];
    short8 b0 = *(const short8*)(w0p + kk * 32);
    short8 b1 = *(const short8*)(w1p + kk * 32);
    acc0 = __builtin_amdgcn_mfma_f32_16x16x32_bf16(a, b0, acc0, 0, 0, 0);
    acc1 = __builtin_amdgcn_mfma_f32_16x16x32_bf16(a, b1, acc1, 0, 0, 0);
  }
  // epilogue: bias, transposed float4 store, channel sum/sumsq
  const int c0 = n0 + l15, c1 = c0 + 16;
  const float bl0 = blv[c0], bl1 = blv[c1];
  float4v o0, o1;
  float s0 = 0.f, q0 = 0.f, s1 = 0.f, q1 = 0.f;
#pragma unroll
  for (int r = 0; r < 4; ++r) {
    float v0 = acc0[r] + bl0; o0[r] = v0; s0 += v0; q0 += v0 * v0;
    float v1 = acc1[r] + bl1; o1[r] = v1; s1 += v1; q1 += v1 * v1;
  }
  *(float4v*)(xout + (size_t)(b * Cn + c0) * Pn + p0 + q * 4) = o0;
  *(float4v*)(xout + (size_t)(b * Cn + c1) * Pn + p0 + q * 4) = o1;
  s0 += __shfl_xor(s0, 16); s0 += __shfl_xor(s0, 32);
  q0 += __shfl_xor(q0, 16); q0 += __shfl_xor(q0, 32);
  s1 += __shfl_xor(s1, 16); s1 += __shfl_xor(s1, 32);
  q1 += __shfl_xor(q1, 16); q1 += __shfl_xor(q1, 32);
  if (lane < 16) {
    atomicAdd(&gacc[c0], s0);
    atomicAdd(&gacc[128 + c0], q0);
    atomicAdd(&gacc[c1], s1);
    atomicAdd(&gacc[128 + c1], q1);
  }
}

// ---------------------------------------------------------------------------
// finalize: layernorm (per-channel over B*P) + relu, in place on x chunk
// ---------------------------------------------------------------------------
__global__ __launch_bounds__(256) void finalize_ln(float* __restrict__ x,
                                                   const float* __restrict__ gacc,
                                                   const float* __restrict__ gamma,
                                                   const float* __restrict__ beta) {
  const int idx = blockIdx.x * 256 + threadIdx.x;
  const int fi = idx * 4;
  const int c = (fi >> 12) & 127;
  const float inv = 1.f / 32768.f;
  const float mean = gacc[c] * inv;
  const float var = gacc[128 + c] * inv - mean * mean;
  const float scale = rsqrtf(var + 1e-5f) * gamma[c];
  const float shift = beta[c] - mean * scale;
  float4v v = *(float4v*)(x + fi);
#pragma unroll
  for (int r = 0; r < 4; ++r) v[r] = fmaxf(v[r] * scale + shift, 0.f);
  *(float4v*)(x + fi) = v;
}

extern "C" void kernel_launch(void* const* d_in, const int* in_sizes, int n_in,
                              void* d_out, int out_size, void* d_ws, size_t ws_size,
                              hipStream_t stream) {
  const float* xyz    = (const float*)d_in[0];
  const float* points = (const float*)d_in[1];
  const float* lc     = (const float*)d_in[2];
  const int*   nl     = (const int*)d_in[3];
  const int*   didx   = (const int*)d_in[4];
  const float* Ww     = (const float*)d_in[5];
  const float* bw     = (const float*)d_in[6];
  const float* Wl     = (const float*)d_in[7];
  const float* bl     = (const float*)d_in[8];
  const float* gamma  = (const float*)d_in[9];
  const float* beta   = (const float*)d_in[10];

  float* out  = (float*)d_out;
  float* xout = out + (size_t)Bn * Pn * 3;                     // x chunk (B,C,P)
  unsigned short* WlT = (unsigned short*)d_ws;                 // 512 KB
  float* gacc = (float*)((char*)d_ws + (size_t)2048 * 128 * 2); // 256 f32

  hipMemcpyAsync(out, xyz, (size_t)Bn * Pn * 3 * sizeof(float),
                 hipMemcpyDeviceToDevice, stream);
  hipMemsetAsync(gacc, 0, 256 * sizeof(float), stream);
  prep_wl<<<16, 256, 0, stream>>>(Wl, WlT);
  fused_conv<<<2048, 256, 0, stream>>>(points, lc, nl, didx, Ww, bw, WlT, bl,
                                       xout, gacc);
  finalize_ln<<<4096, 256, 0, stream>>>(xout, gacc, gamma, beta);
}

// Round 2
// 300.287 us; speedup vs baseline: 1.0318x; 1.0318x over previous
//
#include <hip/hip_runtime.h>

#define Bn 8
#define Nn 4096
#define Pn 4096
#define Kn 32
#define Cn 128

using float4v = __attribute__((ext_vector_type(4))) float;
using short8  = __attribute__((ext_vector_type(8))) short;

__device__ __forceinline__ unsigned short bf16b(float f) {
  union { float f; unsigned u; } v; v.f = f;
  unsigned r = v.u + 0x7FFFu + ((v.u >> 16) & 1u);   // round-nearest-even
  return (unsigned short)(r >> 16);
}

// ---------------------------------------------------------------------------
// prep: WlT[n][k] = bf16(Wl[k][n])   (2048x128 -> 128x2048), 16 blocks
// ---------------------------------------------------------------------------
__global__ __launch_bounds__(256) void prep_wl(const float* __restrict__ Wl,
                                               unsigned short* __restrict__ WlT) {
  __shared__ unsigned short tile[128 * 130];
  const int t = threadIdx.x, blk = blockIdx.x;
#pragma unroll
  for (int i = 0; i < 64; ++i) {
    int idx = i * 256 + t;
    int kl = idx >> 7, n = idx & 127;
    tile[n * 130 + kl] = bf16b(Wl[(size_t)(blk * 128 + kl) * 128 + n]);
  }
  __syncthreads();
#pragma unroll
  for (int i = 0; i < 64; ++i) {
    int idx = i * 256 + t;
    int n = idx >> 7, kl = idx & 127;
    WlT[(size_t)n * 2048 + blk * 128 + kl] = tile[n * 130 + kl];
  }
}

// ---------------------------------------------------------------------------
// stage1: per-wave, no LDS, no barriers.
// Each wave handles 4 points; per point: A-frag = weights (in-register),
// B-frags = direct bf16 gather (high half of f32), 8 MFMAs -> M row (bf16).
// M[b*4096+p][c*16+w], 2048 wide. b = blockIdx&7 for XCD L2 affinity.
// ---------------------------------------------------------------------------
__global__ __launch_bounds__(256) void stage1(
    const float* __restrict__ points, const float* __restrict__ lc,
    const int* __restrict__ nl, const int* __restrict__ didx,
    const float* __restrict__ Ww, const float* __restrict__ bwv,
    unsigned short* __restrict__ Mglob) {
  const int t = threadIdx.x;
  const int lane = t & 63, wave = t >> 6;
  const int l15 = lane & 15, q = lane >> 4;
  const int b = blockIdx.x & 7;          // XCD-affine batch
  const int tile = blockIdx.x >> 3;      // 0..255, 16 points per block
  const int db = didx[b];
  const unsigned short* __restrict__ phi =
      (const unsigned short*)(points + (size_t)db * Nn * Cn);
  const float Ww0 = Ww[l15], Ww1 = Ww[16 + l15], Ww2 = Ww[32 + l15];
  const float bw0 = bwv[l15];

#pragma unroll
  for (int pp = 0; pp < 4; ++pp) {
    const int p = tile * 16 + wave * 4 + pp;
    const size_t pk = (size_t)(db * Pn + p) * Kn;
    // neighbor ids for this lane's k-group (k = q*8+j) — broadcast loads
    const int* __restrict__ nlp = nl + pk + q * 8;
    int nk[8];
#pragma unroll
    for (int j = 0; j < 8; ++j) nk[j] = nlp[j];
    // weights A-frag: A[m=w=l15][k=q*8+j]
    const float* __restrict__ lcp = lc + (pk + q * 8) * 3;
    short8 af;
#pragma unroll
    for (int j = 0; j < 8; ++j) {
      float w = bw0 + lcp[3 * j] * Ww0 + lcp[3 * j + 1] * Ww1 + lcp[3 * j + 2] * Ww2;
      af[j] = (short)bf16b(w);
    }
    unsigned short* __restrict__ mrow = Mglob + ((size_t)b * Pn + p) * 2048;
#pragma unroll
    for (int ct = 0; ct < 8; ++ct) {
      const int c = ct * 16 + l15;
      short8 bfv;
#pragma unroll
      for (int j = 0; j < 8; ++j)
        bfv[j] = (short)phi[((size_t)nk[j] * Cn + c) * 2 + 1];  // trunc->bf16
      float4v d = {0.f, 0.f, 0.f, 0.f};
      d = __builtin_amdgcn_mfma_f32_16x16x32_bf16(af, bfv, d, 0, 0, 0);
      // lane holds M[p][c*16 + (q*4+r)] -> 4 consecutive
      ushort4 u;
      u.x = bf16b(d[0]); u.y = bf16b(d[1]); u.z = bf16b(d[2]); u.w = bf16b(d[3]);
      *(ushort4*)&mrow[c * 16 + q * 4] = u;
    }
  }
}

// ---------------------------------------------------------------------------
// stage2: Y(32768x128) = M(32768x2048) @ Wl(2048x128), no LDS.
// 512 blocks x 64 rows; wave owns cols [32w,32w+32). Frags direct from L1/L2.
// Transposed store into xout(B,C,P) + channel sum/sumsq atomics.
// ---------------------------------------------------------------------------
__global__ __launch_bounds__(256) void stage2(
    const unsigned short* __restrict__ Mglob,
    const unsigned short* __restrict__ WlT, const float* __restrict__ blv,
    float* __restrict__ xout, float* __restrict__ gacc) {
  const int t = threadIdx.x, lane = t & 63, wave = t >> 6;
  const int l15 = lane & 15, q = lane >> 4;
  const int row0 = blockIdx.x * 64;          // global row = b*4096 + p
  const int n0 = wave * 32;

  const unsigned short* __restrict__ a0 = Mglob + (size_t)(row0 + l15) * 2048 + q * 8;
  const unsigned short* __restrict__ b0p = WlT + (size_t)(n0 + l15) * 2048 + q * 8;
  const unsigned short* __restrict__ b1p = b0p + 16 * 2048;

  float4v acc[4][2];
#pragma unroll
  for (int rt = 0; rt < 4; ++rt)
#pragma unroll
    for (int ct = 0; ct < 2; ++ct) acc[rt][ct] = (float4v){0.f, 0.f, 0.f, 0.f};

#pragma unroll 4
  for (int kk = 0; kk < 64; ++kk) {
    const int k0 = kk * 32;
    short8 bf0 = *(const short8*)(b0p + k0);
    short8 bf1 = *(const short8*)(b1p + k0);
#pragma unroll
    for (int rt = 0; rt < 4; ++rt) {
      short8 a = *(const short8*)(a0 + (size_t)rt * 16 * 2048 + k0);
      acc[rt][0] = __builtin_amdgcn_mfma_f32_16x16x32_bf16(a, bf0, acc[rt][0], 0, 0, 0);
      acc[rt][1] = __builtin_amdgcn_mfma_f32_16x16x32_bf16(a, bf1, acc[rt][1], 0, 0, 0);
    }
  }

  // epilogue: bias, store transposed (B,C,P), channel sums
  const int bidx = row0 >> 12;          // batch (64 | 4096, uniform per block)
  const int p0 = row0 & (Pn - 1);
  const int c0 = n0 + l15, c1 = c0 + 16;
  const float bl0 = blv[c0], bl1 = blv[c1];
  float s0 = 0.f, q0 = 0.f, s1 = 0.f, q1 = 0.f;
#pragma unroll
  for (int rt = 0; rt < 4; ++rt) {
    float4v o0, o1;
#pragma unroll
    for (int r = 0; r < 4; ++r) {
      float v0 = acc[rt][0][r] + bl0; o0[r] = v0; s0 += v0; q0 += v0 * v0;
      float v1 = acc[rt][1][r] + bl1; o1[r] = v1; s1 += v1; q1 += v1 * v1;
    }
    const int p = p0 + rt * 16 + q * 4;
    *(float4v*)(xout + ((size_t)bidx * Cn + c0) * Pn + p) = o0;
    *(float4v*)(xout + ((size_t)bidx * Cn + c1) * Pn + p) = o1;
  }
  s0 += __shfl_xor(s0, 16); s0 += __shfl_xor(s0, 32);
  q0 += __shfl_xor(q0, 16); q0 += __shfl_xor(q0, 32);
  s1 += __shfl_xor(s1, 16); s1 += __shfl_xor(s1, 32);
  q1 += __shfl_xor(q1, 16); q1 += __shfl_xor(q1, 32);
  if (lane < 16) {
    atomicAdd(&gacc[c0], s0);
    atomicAdd(&gacc[128 + c0], q0);
    atomicAdd(&gacc[c1], s1);
    atomicAdd(&gacc[128 + c1], q1);
  }
}

// ---------------------------------------------------------------------------
// finalize: layernorm (per-channel over B*P) + relu, in place on x chunk
// ---------------------------------------------------------------------------
__global__ __launch_bounds__(256) void finalize_ln(float* __restrict__ x,
                                                   const float* __restrict__ gacc,
                                                   const float* __restrict__ gamma,
                                                   const float* __restrict__ beta) {
  const int idx = blockIdx.x * 256 + threadIdx.x;
  const int fi = idx * 4;
  const int c = (fi >> 12) & 127;
  const float inv = 1.f / 32768.f;
  const float mean = gacc[c] * inv;
  const float var = gacc[128 + c] * inv - mean * mean;
  const float scale = rsqrtf(var + 1e-5f) * gamma[c];
  const float shift = beta[c] - mean * scale;
  float4v v = *(float4v*)(x + fi);
#pragma unroll
  for (int r = 0; r < 4; ++r) v[r] = fmaxf(v[r] * scale + shift, 0.f);
  *(float4v*)(x + fi) = v;
}

extern "C" void kernel_launch(void* const* d_in, const int* in_sizes, int n_in,
                              void* d_out, int out_size, void* d_ws, size_t ws_size,
                              hipStream_t stream) {
  const float* xyz    = (const float*)d_in[0];
  const float* points = (const float*)d_in[1];
  const float* lc     = (const float*)d_in[2];
  const int*   nl     = (const int*)d_in[3];
  const int*   didx   = (const int*)d_in[4];
  const float* Ww     = (const float*)d_in[5];
  const float* bw     = (const float*)d_in[6];
  const float* Wl     = (const float*)d_in[7];
  const float* bl     = (const float*)d_in[8];
  const float* gamma  = (const float*)d_in[9];
  const float* beta   = (const float*)d_in[10];

  float* out  = (float*)d_out;
  float* xout = out + (size_t)Bn * Pn * 3;                       // x chunk (B,C,P)
  unsigned short* WlT = (unsigned short*)d_ws;                   // 512 KB
  float* gacc = (float*)((char*)d_ws + (size_t)512 * 1024);      // 1 KB
  unsigned short* Mglob =
      (unsigned short*)((char*)d_ws + (size_t)1024 * 1024);      // 128 MB

  hipMemcpyAsync(out, xyz, (size_t)Bn * Pn * 3 * sizeof(float),
                 hipMemcpyDeviceToDevice, stream);
  hipMemsetAsync(gacc, 0, 256 * sizeof(float), stream);
  prep_wl<<<16, 256, 0, stream>>>(Wl, WlT);
  stage1<<<2048, 256, 0, stream>>>(points, lc, nl, didx, Ww, bw, Mglob);
  stage2<<<512, 256, 0, stream>>>(Mglob, WlT, bl, xout, gacc);
  finalize_ln<<<4096, 256, 0, stream>>>(xout, gacc, gamma, beta);
}

// Round 3
// 242.506 us; speedup vs baseline: 1.2776x; 1.2383x over previous
//
#include <hip/hip_runtime.h>

#define Bn 8
#define Nn 4096
#define Pn 4096
#define Kn 32
#define Cn 128

using float4v = __attribute__((ext_vector_type(4))) float;
using short8  = __attribute__((ext_vector_type(8))) short;

__device__ __forceinline__ unsigned short bf16b(float f) {
  union { float f; unsigned u; } v; v.f = f;
  unsigned r = v.u + 0x7FFFu + ((v.u >> 16) & 1u);   // round-nearest-even
  return (unsigned short)(r >> 16);
}

__device__ __forceinline__ void gld_lds16(const void* g, void* l) {
  __builtin_amdgcn_global_load_lds(
      (const __attribute__((address_space(1))) unsigned int*)g,
      (__attribute__((address_space(3))) unsigned int*)l, 16, 0, 0);
}

// ---------------------------------------------------------------------------
// prep: WlT[n][k] = bf16(Wl[k][n])   (2048x128 -> 128x2048), 16 blocks
// ---------------------------------------------------------------------------
__global__ __launch_bounds__(256) void prep_wl(const float* __restrict__ Wl,
                                               unsigned short* __restrict__ WlT) {
  __shared__ unsigned short tile[128 * 130];
  const int t = threadIdx.x, blk = blockIdx.x;
#pragma unroll
  for (int i = 0; i < 64; ++i) {
    int idx = i * 256 + t;
    int kl = idx >> 7, n = idx & 127;
    tile[n * 130 + kl] = bf16b(Wl[(size_t)(blk * 128 + kl) * 128 + n]);
  }
  __syncthreads();
#pragma unroll
  for (int i = 0; i < 64; ++i) {
    int idx = i * 256 + t;
    int n = idx >> 7, kl = idx & 127;
    WlT[(size_t)n * 2048 + blk * 128 + kl] = tile[n * 130 + kl];
  }
}

// ---------------------------------------------------------------------------
// stage1: per-wave, no LDS, no barriers. 32-bit saddr+voffset gather.
// Each wave handles 4 points; per point: A-frag = weights (in-register),
// B-frags = direct bf16 gather (high half of f32), 8 MFMAs -> M row (bf16).
// ---------------------------------------------------------------------------
__global__ __launch_bounds__(256) void stage1(
    const float* __restrict__ points, const float* __restrict__ lc,
    const int* __restrict__ nl, const int* __restrict__ didx,
    const float* __restrict__ Ww, const float* __restrict__ bwv,
    unsigned short* __restrict__ Mglob) {
  const int t = threadIdx.x;
  const int lane = t & 63, wave = t >> 6;
  const int l15 = lane & 15, q = lane >> 4;
  const int b = blockIdx.x & 7;          // XCD-affine batch
  const int tile = blockIdx.x >> 3;      // 0..255, 16 points per block
  const int db = didx[b];
  const unsigned short* __restrict__ phi =
      (const unsigned short*)(points + (size_t)db * Nn * Cn);
  const float Ww0 = Ww[l15], Ww1 = Ww[16 + l15], Ww2 = Ww[32 + l15];
  const float bw0 = bwv[l15];
  const unsigned cb = (unsigned)(l15 << 1) + 1u;   // odd ushort = f32 high half

#pragma unroll
  for (int pp = 0; pp < 4; ++pp) {
    const int p = tile * 16 + wave * 4 + pp;
    const size_t pk = (size_t)(db * Pn + p) * Kn;
    const int* __restrict__ nlp = nl + pk + q * 8;
    unsigned off8[8];
#pragma unroll
    for (int j = 0; j < 8; ++j) off8[j] = ((unsigned)nlp[j] << 8) + cb;
    // weights A-frag: A[m=w=l15][k=q*8+j]
    const float* __restrict__ lcp = lc + (pk + q * 8) * 3;
    short8 af;
#pragma unroll
    for (int j = 0; j < 8; ++j) {
      float w = bw0 + lcp[3 * j] * Ww0 + lcp[3 * j + 1] * Ww1 + lcp[3 * j + 2] * Ww2;
      af[j] = (short)bf16b(w);
    }
    unsigned short* __restrict__ mrow = Mglob + ((size_t)b * Pn + p) * 2048;
#pragma unroll
    for (int ct = 0; ct < 8; ++ct) {
      short8 bfv;
#pragma unroll
      for (int j = 0; j < 8; ++j)
        bfv[j] = (short)phi[off8[j] + ct * 32];   // imm offset, trunc->bf16
      float4v d = {0.f, 0.f, 0.f, 0.f};
      d = __builtin_amdgcn_mfma_f32_16x16x32_bf16(af, bfv, d, 0, 0, 0);
      const int c = ct * 16 + l15;
      ushort4 u;
      u.x = bf16b(d[0]); u.y = bf16b(d[1]); u.z = bf16b(d[2]); u.w = bf16b(d[3]);
      *(ushort4*)&mrow[c * 16 + q * 4] = u;
    }
  }
}

// ---------------------------------------------------------------------------
// stage2: Y(32768x128) = M(32768x2048) @ Wl(2048x128).
// 512 blocks, 64 rows x 128 cols each; BK=64 chunks staged to LDS via
// global_load_lds(16B) with XOR chunk swizzle (conflict-free ds_read_b128).
// ---------------------------------------------------------------------------
__global__ __launch_bounds__(256) void stage2(
    const unsigned short* __restrict__ Mglob,
    const unsigned short* __restrict__ WlT, const float* __restrict__ blv,
    float* __restrict__ xout, float* __restrict__ gacc) {
  __shared__ unsigned short As[64 * 64];    // [row][chunk] chunks XOR-swizzled
  __shared__ unsigned short Bs[128 * 64];
  __shared__ float red[4][256];

  const int t = threadIdx.x, lane = t & 63, wave = t >> 6;
  const int l15 = lane & 15, q = lane >> 4;
  const int bidx = blockIdx.x & 7;                 // XCD-affine batch
  const int p0 = (blockIdx.x >> 3) * 64;
  const size_t row0 = (size_t)bidx * Pn + p0;
  const int lr = lane >> 3, lchk = lane & 7;

  float4v acc[8];
#pragma unroll
  for (int nt = 0; nt < 8; ++nt) acc[nt] = (float4v){0.f, 0.f, 0.f, 0.f};

  for (int kk = 0; kk < 32; ++kk) {
    const int k0 = kk * 64;
    // stage A-tile: 64 rows x 64 k (8 KB); wave w: rows [16w,16w+16)
#pragma unroll
    for (int it = 0; it < 2; ++it) {
      const int row = wave * 16 + it * 8 + lr;
      const int cg = lchk ^ (row & 7);
      gld_lds16(Mglob + (row0 + row) * 2048 + k0 + cg * 8,
                &As[(wave * 16 + it * 8) * 64]);
    }
    // stage B-tile: 128 n x 64 k (16 KB); wave w: n [32w,32w+32)
#pragma unroll
    for (int it = 0; it < 4; ++it) {
      const int n = wave * 32 + it * 8 + lr;
      const int cg = lchk ^ (n & 7);
      gld_lds16(WlT + (size_t)n * 2048 + k0 + cg * 8,
                &Bs[(wave * 32 + it * 8) * 64]);
    }
    __syncthreads();
    short8 af[2];
#pragma unroll
    for (int ks = 0; ks < 2; ++ks)
      af[ks] = *(const short8*)
          &As[(wave * 16 + l15) * 64 + (((ks * 4 + q) ^ (l15 & 7)) << 3)];
#pragma unroll
    for (int nt = 0; nt < 8; ++nt) {
#pragma unroll
      for (int ks = 0; ks < 2; ++ks) {
        short8 bf = *(const short8*)
            &Bs[(nt * 16 + l15) * 64 + (((ks * 4 + q) ^ (l15 & 7)) << 3)];
        acc[nt] = __builtin_amdgcn_mfma_f32_16x16x32_bf16(af[ks], bf, acc[nt], 0, 0, 0);
      }
    }
    __syncthreads();
  }

  // epilogue: bias, transposed store (B,C,P), block-reduced channel stats
  const int pw = p0 + wave * 16 + q * 4;
#pragma unroll
  for (int nt = 0; nt < 8; ++nt) {
    const int ch = nt * 16 + l15;
    const float bb = blv[ch];
    float4v o;
    float s = 0.f, sq = 0.f;
#pragma unroll
    for (int r = 0; r < 4; ++r) {
      float v = acc[nt][r] + bb; o[r] = v; s += v; sq += v * v;
    }
    *(float4v*)(xout + ((size_t)bidx * Cn + ch) * Pn + pw) = o;
    s += __shfl_xor(s, 16); s += __shfl_xor(s, 32);
    sq += __shfl_xor(sq, 16); sq += __shfl_xor(sq, 32);
    if (lane < 16) { red[wave][ch] = s; red[wave][128 + ch] = sq; }
  }
  __syncthreads();
  const float v = red[0][t] + red[1][t] + red[2][t] + red[3][t];
  atomicAdd(&gacc[t], v);
}

// ---------------------------------------------------------------------------
// finalize: layernorm (per-channel over B*P) + relu, in place on x chunk
// ---------------------------------------------------------------------------
__global__ __launch_bounds__(256) void finalize_ln(float* __restrict__ x,
                                                   const float* __restrict__ gacc,
                                                   const float* __restrict__ gamma,
                                                   const float* __restrict__ beta) {
  const int idx = blockIdx.x * 256 + threadIdx.x;
  const int fi = idx * 4;
  const int c = (fi >> 12) & 127;
  const float inv = 1.f / 32768.f;
  const float mean = gacc[c] * inv;
  const float var = gacc[128 + c] * inv - mean * mean;
  const float scale = rsqrtf(var + 1e-5f) * gamma[c];
  const float shift = beta[c] - mean * scale;
  float4v v = *(float4v*)(x + fi);
#pragma unroll
  for (int r = 0; r < 4; ++r) v[r] = fmaxf(v[r] * scale + shift, 0.f);
  *(float4v*)(x + fi) = v;
}

extern "C" void kernel_launch(void* const* d_in, const int* in_sizes, int n_in,
                              void* d_out, int out_size, void* d_ws, size_t ws_size,
                              hipStream_t stream) {
  const float* xyz    = (const float*)d_in[0];
  const float* points = (const float*)d_in[1];
  const float* lc     = (const float*)d_in[2];
  const int*   nl     = (const int*)d_in[3];
  const int*   didx   = (const int*)d_in[4];
  const float* Ww     = (const float*)d_in[5];
  const float* bw     = (const float*)d_in[6];
  const float* Wl     = (const float*)d_in[7];
  const float* bl     = (const float*)d_in[8];
  const float* gamma  = (const float*)d_in[9];
  const float* beta   = (const float*)d_in[10];

  float* out  = (float*)d_out;
  float* xout = out + (size_t)Bn * Pn * 3;                       // x chunk (B,C,P)
  unsigned short* WlT = (unsigned short*)d_ws;                   // 512 KB
  float* gacc = (float*)((char*)d_ws + (size_t)512 * 1024);      // 1 KB
  unsigned short* Mglob =
      (unsigned short*)((char*)d_ws + (size_t)1024 * 1024);      // 128 MB

  hipMemcpyAsync(out, xyz, (size_t)Bn * Pn * 3 * sizeof(float),
                 hipMemcpyDeviceToDevice, stream);
  hipMemsetAsync(gacc, 0, 256 * sizeof(float), stream);
  prep_wl<<<16, 256, 0, stream>>>(Wl, WlT);
  stage1<<<2048, 256, 0, stream>>>(points, lc, nl, didx, Ww, bw, Mglob);
  stage2<<<512, 256, 0, stream>>>(Mglob, WlT, bl, xout, gacc);
  finalize_ln<<<4096, 256, 0, stream>>>(xout, gacc, gamma, beta);
}